// Round 13
// baseline (95.600 us; speedup 1.0000x reference)
//
#include <hip/hip_runtime.h>
#include <cstdint>
#include <cstddef>

typedef __attribute__((ext_vector_type(8))) short bf16x8;
typedef __attribute__((ext_vector_type(4))) float f32x4;
typedef unsigned short u16;

#define QSCALE (0.125f * 1.44269504088896f)  // fold softmax scale + log2e into Q

__device__ inline u16 f2bf(float x) {
  uint32_t u = __builtin_bit_cast(uint32_t, x);
  u += 0x7FFFu + ((u >> 16) & 1u);
  return (u16)(u >> 16);
}
__device__ inline float bf2f(u16 v) {
  return __builtin_bit_cast(float, (uint32_t)v << 16);
}
__device__ inline uint32_t cvtpk(float a, float b) {
  uint32_t r;
  asm("v_cvt_pk_bf16_f32 %0, %1, %2" : "=v"(r) : "v"(a), "v"(b));
  return r;
}
__device__ inline float exp2raw(float x) {  // bare v_exp_f32, no libm fixup
  float r;
  asm("v_exp_f32 %0, %1" : "=v"(r) : "v"(x));
  return r;
}
__device__ inline void gload_lds16(const void* g, void* l) {
  __builtin_amdgcn_global_load_lds(
      (const __attribute__((address_space(1))) char*)g,
      (__attribute__((address_space(3))) char*)l, 16, 0, 0);
}

// ---------------- prep_a: gn partial sums + weight cvt + ctx transpose -------
__global__ __launch_bounds__(256) void prep_a(const float* __restrict__ x,
                                              float* __restrict__ gpart,
                                              float* __restrict__ gpart2,
                                              const float* __restrict__ wq, u16* __restrict__ wqB,
                                              const float* __restrict__ wk, u16* __restrict__ wkB,
                                              const float* __restrict__ wv, u16* __restrict__ wvB,
                                              const float* __restrict__ wo, u16* __restrict__ woB,
                                              const float* __restrict__ ctx, u16* __restrict__ ctxT) {
  int b = blockIdx.x;
  int t = threadIdx.x;
  if (b < 256) {
    __shared__ float rs[4], rss[4];
    int g = b >> 3, sl = b & 7;
    const float* base = x + (size_t)g * 65536 + sl * 8192;
    float s = 0.f, ss = 0.f;
#pragma unroll
    for (int i = 0; i < 8; ++i) {
      float4 v = *reinterpret_cast<const float4*>(base + i * 1024 + t * 4);
      s += v.x + v.y + v.z + v.w;
      ss += v.x * v.x + v.y * v.y + v.z * v.z + v.w * v.w;
    }
    for (int d = 32; d; d >>= 1) {
      s += __shfl_down(s, d, 64);
      ss += __shfl_down(ss, d, 64);
    }
    int wid = t >> 6;
    if ((t & 63) == 0) { rs[wid] = s; rss[wid] = ss; }
    __syncthreads();
    if (t == 0) {
      gpart[b] = rs[0] + rs[1] + rs[2] + rs[3];
      gpart2[b] = rss[0] + rss[1] + rss[2] + rss[3];
    }
    return;
  }
  if (b < 1536) {
    int off = b - 256;
    const float* s; u16* d;
    if (off < 256)       { s = wq; d = wqB; }
    else if (off < 640)  { s = wk; d = wkB; off -= 256; }
    else if (off < 1024) { s = wv; d = wvB; off -= 640; }
    else                 { s = wo; d = woB; off -= 1024; }
    int i = (off * 256 + t) * 4;
    float4 v = *reinterpret_cast<const float4*>(s + i);
    u16 o[4] = {f2bf(v.x), f2bf(v.y), f2bf(v.z), f2bf(v.w)};
    *reinterpret_cast<uint2*>(d + i) = *reinterpret_cast<const uint2*>(o);
    return;
  }
  __shared__ float tile[64][65];
  int idx = b - 1536;
  int p0 = (idx & 63) * 64, c0 = (idx >> 6) * 64;
  int cl = t >> 4, pl = (t & 15) * 4;
#pragma unroll
  for (int rep = 0; rep < 4; ++rep) {
    int c = cl + rep * 16;
    float4 v = *reinterpret_cast<const float4*>(ctx + (size_t)(c0 + c) * 4096 + p0 + pl);
    tile[c][pl + 0] = v.x;
    tile[c][pl + 1] = v.y;
    tile[c][pl + 2] = v.z;
    tile[c][pl + 3] = v.w;
  }
  __syncthreads();
#pragma unroll
  for (int rep = 0; rep < 16; ++rep) {
    int id2 = rep * 256 + t;
    int pw = id2 >> 6, cw = id2 & 63;
    ctxT[(size_t)(p0 + pw) * 768 + c0 + cw] = f2bf(tile[cw][pw]);
  }
}

// ---------------- prep_b: x groupnorm + transpose to hT ----------------------
__global__ __launch_bounds__(256) void prep_b(const float* __restrict__ x,
                                              u16* __restrict__ hT,
                                              const float* __restrict__ gnw, const float* __restrict__ gnb,
                                              const float* __restrict__ gpart, const float* __restrict__ gpart2) {
  __shared__ float tile[64][65];
  __shared__ float smu[4], srs[4];
  int b = blockIdx.x;
  int t = threadIdx.x;
  int p0 = (b & 63) * 64, c0 = (b >> 6) * 64;
  if (t < 4) {
    int g = (c0 >> 4) + t;
    float S = 0.f, SS = 0.f;
#pragma unroll
    for (int sIdx = 0; sIdx < 8; ++sIdx) {
      S += gpart[g * 8 + sIdx];
      SS += gpart2[g * 8 + sIdx];
    }
    float mu = S * (1.f / 65536.f);
    float var = SS * (1.f / 65536.f) - mu * mu;
    smu[t] = mu;
    srs[t] = rsqrtf(var + 1e-5f);
  }
  __syncthreads();
  int cl = t >> 4, pl = (t & 15) * 4;
#pragma unroll
  for (int rep = 0; rep < 4; ++rep) {
    int c = cl + rep * 16;
    float4 v = *reinterpret_cast<const float4*>(x + (size_t)(c0 + c) * 4096 + p0 + pl);
    float s = gnw[c0 + c] * srs[rep];
    float f = gnb[c0 + c] - smu[rep] * s;
    tile[c][pl + 0] = v.x * s + f;
    tile[c][pl + 1] = v.y * s + f;
    tile[c][pl + 2] = v.z * s + f;
    tile[c][pl + 3] = v.w * s + f;
  }
  __syncthreads();
#pragma unroll
  for (int rep = 0; rep < 16; ++rep) {
    int idx = rep * 256 + t;
    int pw = idx >> 6, cw = idx & 63;
    hT[(size_t)(p0 + pw) * 512 + c0 + cw] = f2bf(tile[cw][pw]);
  }
}

// ---------------- NT GEMM body: D[i][j] = sum_k A[i][k]*B[j][k] --------------
// BM=128, BN=NF*32 (NF=2 or 4). 2-buffer LDS, 1-ahead prefetch.
template <int NF, int BIAS_MODE>
__device__ inline void gemm_body(u16* __restrict__ aT, u16* __restrict__ bT,
                                 const u16* __restrict__ A, const u16* __restrict__ B,
                                 u16* __restrict__ Dv,
                                 const float* __restrict__ bias,
                                 int Rb, int K, float oscale, int bx, int by) {
  constexpr int BN = NF * 32;
  constexpr int BBUF = BN * 64;  // u16 elements per B buffer
  const int t = threadIdx.x;
  const int lane = t & 63, w = t >> 6;
  const int wr = w >> 1, wc = w & 1;
  const int l15 = lane & 15, l4 = lane >> 4;
  const int i0 = by * 128, j0 = bx * BN;
  const int r_st = t >> 3, slot = t & 7;
  f32x4 acc[4][NF] = {};

  auto stage = [&](int kt, int b) {
#pragma unroll
    for (int q = 0; q < 4; ++q) {
      int row = q * 32 + r_st;
      int koff = kt + ((slot ^ (row & 7)) * 8);
      gload_lds16(A + (size_t)(i0 + row) * K + koff, (char*)aT + b * 16384 + q * 4096 + w * 1024);
    }
#pragma unroll
    for (int q = 0; q < NF; ++q) {
      int row = q * 32 + r_st;
      int koff = kt + ((slot ^ (row & 7)) * 8);
      gload_lds16(B + (size_t)(j0 + row) * K + koff, (char*)bT + b * BBUF * 2 + q * 4096 + w * 1024);
    }
  };

  const int nt = K / 64;
  stage(0, 0);

  for (int tt = 0; tt < nt; ++tt) {
    const int cur = tt & 1;
    asm volatile("s_waitcnt vmcnt(0)\n\ts_barrier" ::: "memory");
    if (tt + 1 < nt) stage((tt + 1) * 64, cur ^ 1);

#pragma unroll
    for (int kk = 0; kk < 2; ++kk) {
      bf16x8 af[4], bfr[NF];
#pragma unroll
      for (int m = 0; m < 4; ++m) {
        int row = wr * 64 + m * 16 + l15;
        int off = row * 128 + ((l4 * 16 + kk * 64) ^ ((row & 7) << 4));
        af[m] = *reinterpret_cast<const bf16x8*>((const char*)aT + cur * 16384 + off);
      }
#pragma unroll
      for (int n = 0; n < NF; ++n) {
        int row = wc * (BN / 2) + n * 16 + l15;
        int off = row * 128 + ((l4 * 16 + kk * 64) ^ ((row & 7) << 4));
        bfr[n] = *reinterpret_cast<const bf16x8*>((const char*)bT + cur * BBUF * 2 + off);
      }
#pragma unroll
      for (int m = 0; m < 4; ++m)
#pragma unroll
        for (int n = 0; n < NF; ++n)
          acc[m][n] = __builtin_amdgcn_mfma_f32_16x16x32_bf16(af[m], bfr[n], acc[m][n], 0, 0, 0);
    }
  }

#pragma unroll
  for (int m = 0; m < 4; ++m) {
    int ib = i0 + wr * 64 + m * 16 + l4 * 4;
#pragma unroll
    for (int n = 0; n < NF; ++n) {
      int j = j0 + wc * (BN / 2) + n * 16 + l15;
#pragma unroll
      for (int r = 0; r < 4; ++r) {
        int i = ib + r;
        float v = acc[m][n][r];
        if (BIAS_MODE == 0) v += bias[i];
        else v += bias[j];
        v *= oscale;
        Dv[(size_t)i * Rb + j] = f2bf(v);
      }
    }
  }
}

// merged Q+K+V projections, 512 blocks (Q,K: BN=128; V: BN=64). 64KB LDS -> 2/CU
__global__ __launch_bounds__(256) void gemm_all(const u16* __restrict__ hT, const u16* __restrict__ ctxT,
                                                const u16* __restrict__ wqB, const u16* __restrict__ wkB,
                                                const u16* __restrict__ wvB,
                                                u16* __restrict__ QT, u16* __restrict__ KT, u16* __restrict__ Vb,
                                                const float* __restrict__ bq, const float* __restrict__ bk,
                                                const float* __restrict__ bv) {
  __shared__ u16 aT[2][128 * 64];
  __shared__ u16 bT[2][128 * 64];
  int b = blockIdx.x;
  if (b < 128)
    gemm_body<4, 1>(&aT[0][0], &bT[0][0], hT, wqB, QT, bq, 512, 512, QSCALE, b & 3, b >> 2);
  else if (b < 256)
    gemm_body<4, 1>(&aT[0][0], &bT[0][0], ctxT, wkB, KT, bk, 512, 768, 1.0f, (b - 128) & 3, (b - 128) >> 2);
  else
    gemm_body<2, 0>(&aT[0][0], &bT[0][0], wvB, ctxT, Vb, bv, 4096, 768, 1.0f, (b - 256) & 63, (b - 256) >> 6);
}

// ---------------- fused combine + output projection + residual ---------------
// BM=64 -> 512 blocks (2/CU). A = woB via gload_lds 3-buf; B reg-staged.
__global__ __launch_bounds__(256) void gemm_projF(const u16* __restrict__ woB,
                                                  const u16* __restrict__ P0, const u16* __restrict__ P1,
                                                  const u16* __restrict__ P2, const u16* __restrict__ P3,
                                                  const float* __restrict__ Lb,
                                                  float* __restrict__ D, const float* __restrict__ bo,
                                                  const float* __restrict__ res) {
  __shared__ u16 aT[3][64 * 64];
  __shared__ u16 bT[2][64 * 64];
  __shared__ float sinv[512];  // [h][j_local]
  const int t = threadIdx.x;
  const int lane = t & 63, w = t >> 6;
  const int wr = w >> 1, wc = w & 1;
  const int l15 = lane & 15, l4 = lane >> 4;
  const int bx = blockIdx.x & 63, by = blockIdx.x >> 6;
  const int i0 = by * 64, j0 = bx * 64;
  const int r_st = t >> 3, slot = t & 7;

  {
#pragma unroll
    for (int r = 0; r < 2; ++r) {
      int idx = t * 2 + r;
      int hh = idx >> 6, jj = idx & 63;
      int o = hh * 4096 + j0 + jj;
      float den = Lb[o] + Lb[32768 + o] + Lb[65536 + o] + Lb[98304 + o];
      sinv[idx] = 1.f / den;
    }
  }

  auto stageA = [&](int kt, int b) {
#pragma unroll
    for (int q = 0; q < 2; ++q) {
      int row = q * 32 + r_st;
      int koff = kt + ((slot ^ (row & 7)) * 8);
      gload_lds16(woB + (size_t)(i0 + row) * 512 + koff, (char*)aT + b * 8192 + q * 4096 + w * 1024);
    }
  };

  const int brow = t >> 2;        // 0..63: token row within tile
  const int bc0 = (t & 3) * 2;    // first of 2 chunks (8 bf16 each)
  uint4 rv[2][4];
  auto loadB = [&](int kt) {
#pragma unroll
    for (int c = 0; c < 2; ++c) {
      size_t off = (size_t)(j0 + brow) * 512 + kt + (bc0 + c) * 8;
      rv[c][0] = *reinterpret_cast<const uint4*>(P0 + off);
      rv[c][1] = *reinterpret_cast<const uint4*>(P1 + off);
      rv[c][2] = *reinterpret_cast<const uint4*>(P2 + off);
      rv[c][3] = *reinterpret_cast<const uint4*>(P3 + off);
    }
  };
  auto writeB = [&](int kt, int buf) {
    float inv = sinv[((kt >> 6) << 6) + brow];
#pragma unroll
    for (int c = 0; c < 2; ++c) {
      uint32_t pk[4];
#pragma unroll
      for (int wi = 0; wi < 4; ++wi) {
        uint32_t w0 = (wi == 0) ? rv[c][0].x : (wi == 1) ? rv[c][0].y : (wi == 2) ? rv[c][0].z : rv[c][0].w;
        uint32_t w1 = (wi == 0) ? rv[c][1].x : (wi == 1) ? rv[c][1].y : (wi == 2) ? rv[c][1].z : rv[c][1].w;
        uint32_t w2 = (wi == 0) ? rv[c][2].x : (wi == 1) ? rv[c][2].y : (wi == 2) ? rv[c][2].z : rv[c][2].w;
        uint32_t w3 = (wi == 0) ? rv[c][3].x : (wi == 1) ? rv[c][3].y : (wi == 2) ? rv[c][3].z : rv[c][3].w;
        float lo = __builtin_bit_cast(float, w0 << 16) + __builtin_bit_cast(float, w1 << 16) +
                   __builtin_bit_cast(float, w2 << 16) + __builtin_bit_cast(float, w3 << 16);
        float hi = __builtin_bit_cast(float, w0 & 0xFFFF0000u) + __builtin_bit_cast(float, w1 & 0xFFFF0000u) +
                   __builtin_bit_cast(float, w2 & 0xFFFF0000u) + __builtin_bit_cast(float, w3 & 0xFFFF0000u);
        pk[wi] = cvtpk(lo * inv, hi * inv);
      }
      uint4 outv = {pk[0], pk[1], pk[2], pk[3]};
      int off = brow * 128 + (((bc0 + c) ^ (brow & 7)) * 16);
      *reinterpret_cast<uint4*>((char*)&bT[buf][0] + off) = outv;
    }
  };

  stageA(0, 0);
  stageA(64, 1);
  loadB(0);
  asm volatile("s_waitcnt vmcnt(2)" ::: "memory");  // A(0) drained; rv compiler-guarded
  writeB(0, 0);
  asm volatile("s_waitcnt lgkmcnt(0)\n\ts_barrier" ::: "memory");

  f32x4 acc[2][2] = {};
  for (int tt = 0; tt < 8; ++tt) {
    const int cur = tt & 1;
    if (tt + 1 < 8) loadB((tt + 1) * 64);

#pragma unroll
    for (int kk = 0; kk < 2; ++kk) {
      bf16x8 af[2], bfr[2];
#pragma unroll
      for (int m = 0; m < 2; ++m) {
        int row = wr * 32 + m * 16 + l15;
        int off = row * 128 + ((l4 * 16 + kk * 64) ^ ((row & 7) << 4));
        af[m] = *reinterpret_cast<const bf16x8*>((const char*)aT + (tt % 3) * 8192 + off);
      }
#pragma unroll
      for (int n = 0; n < 2; ++n) {
        int row = wc * 32 + n * 16 + l15;
        int off = row * 128 + ((l4 * 16 + kk * 64) ^ ((row & 7) << 4));
        bfr[n] = *reinterpret_cast<const bf16x8*>((const char*)&bT[cur][0] + off);
      }
#pragma unroll
      for (int m = 0; m < 2; ++m)
#pragma unroll
        for (int n = 0; n < 2; ++n)
          acc[m][n] = __builtin_amdgcn_mfma_f32_16x16x32_bf16(af[m], bfr[n], acc[m][n], 0, 0, 0);
    }

    if (tt + 2 < 8) stageA((tt + 2) * 64, (tt + 2) % 3);
    if (tt + 1 < 8) {
      if (tt + 2 < 8) asm volatile("s_waitcnt vmcnt(2)" ::: "memory");
      else            asm volatile("s_waitcnt vmcnt(0)" ::: "memory");
      writeB((tt + 1) * 64, cur ^ 1);
    }
    asm volatile("s_waitcnt lgkmcnt(0)\n\ts_barrier" ::: "memory");
  }

#pragma unroll
  for (int m = 0; m < 2; ++m) {
    int ib = i0 + wr * 32 + m * 16 + l4 * 4;
#pragma unroll
    for (int n = 0; n < 2; ++n) {
      int j = j0 + wc * 32 + n * 16 + l15;
#pragma unroll
      for (int r = 0; r < 4; ++r) {
        int i = ib + r;
        float v = acc[m][n][r] + bo[i] + res[(size_t)i * 4096 + j];
        D[(size_t)i * 4096 + j] = v;
      }
    }
  }
}

// ---------------- flash attention: fixed-offset softmax, KV-split x4 ---------
// (r10 kernel, verbatim — known race-free)
__global__ __launch_bounds__(256) void attn_kernel(const u16* __restrict__ QT,
                                                   const u16* __restrict__ KT,
                                                   const u16* __restrict__ V,
                                                   u16* __restrict__ P0, u16* __restrict__ P1,
                                                   u16* __restrict__ P2, u16* __restrict__ P3,
                                                   float* __restrict__ Lb) {
  __shared__ u16 kbuf[2][64 * 64];
  __shared__ u16 vbuf[2][64 * 64];
  const int t = threadIdx.x;
  const int lane = t & 63, w = t >> 6;
  const int l15 = lane & 15, l4 = lane >> 4;
  int id = blockIdx.x;
  id = (id & 7) * 128 + (id >> 3);
  const int z = id >> 8;
  const int h = (id >> 5) & 7;
  const int q0 = (id & 31) * 128;
  const int tile0 = z * 16;
  const int r_st = t >> 3, slot = t & 7;

  bf16x8 qa[2][2];
#pragma unroll
  for (int f = 0; f < 2; ++f) {
    int qrow = q0 + w * 32 + f * 16 + l15;
    qa[f][0] = *reinterpret_cast<const bf16x8*>(QT + (size_t)qrow * 512 + h * 64 + l4 * 8);
    qa[f][1] = *reinterpret_cast<const bf16x8*>(QT + (size_t)qrow * 512 + h * 64 + 32 + l4 * 8);
  }

  f32x4 o0[4] = {}, o1[4] = {};
  f32x4 la0 = {}, la1 = {};
  const short oneb = (short)0x3F80;
  const bf16x8 ones = {oneb, oneb, oneb, oneb, oneb, oneb, oneb, oneb};

  int off0[4], off1[4];
#pragma unroll
  for (int n = 0; n < 4; ++n) {
    int row = n * 16 + l15, sw = (row & 7) << 4;
    off0[n] = row * 128 + ((l4 * 16) ^ sw);
    off1[n] = row * 128 + ((l4 * 16 + 64) ^ sw);
  }

  auto stageK = [&](int tile, int b) {
#pragma unroll
    for (int q = 0; q < 2; ++q) {
      int row = q * 32 + r_st;
      int so = (slot ^ (row & 7)) * 8;
      gload_lds16(KT + (size_t)(tile * 64 + row) * 512 + h * 64 + so,
                  (char*)kbuf[b] + q * 4096 + w * 1024);
    }
  };
  auto stageV = [&](int tile, int b) {
#pragma unroll
    for (int q = 0; q < 2; ++q) {
      int row = q * 32 + r_st;
      int so = ((((slot & 1) * 4 + (slot >> 1)) ^ (row & 7)) * 8);
      gload_lds16(V + (size_t)(h * 64 + row) * 4096 + tile * 64 + so,
                  (char*)vbuf[b] + q * 4096 + w * 1024);
    }
  };

  stageK(tile0, 0);
  stageV(tile0, 0);

#pragma unroll 2
  for (int kt = 0; kt < 16; ++kt) {
    const int cur = kt & 1;
    asm volatile("s_waitcnt vmcnt(0)\n\ts_barrier" ::: "memory");
    if (kt + 1 < 16) { stageK(tile0 + kt + 1, cur ^ 1); stageV(tile0 + kt + 1, cur ^ 1); }

    f32x4 s0[4], s1[4];
#pragma unroll
    for (int n = 0; n < 4; ++n) {
      bf16x8 kb0 = *reinterpret_cast<const bf16x8*>((const char*)kbuf[cur] + off0[n]);
      bf16x8 kb1 = *reinterpret_cast<const bf16x8*>((const char*)kbuf[cur] + off1[n]);
      f32x4 za = {};
      za = __builtin_amdgcn_mfma_f32_16x16x32_bf16(kb0, qa[0][0], za, 0, 0, 0);
      za = __builtin_amdgcn_mfma_f32_16x16x32_bf16(kb1, qa[0][1], za, 0, 0, 0);
      s0[n] = za;
      f32x4 zb = {};
      zb = __builtin_amdgcn_mfma_f32_16x16x32_bf16(kb0, qa[1][0], zb, 0, 0, 0);
      zb = __builtin_amdgcn_mfma_f32_16x16x32_bf16(kb1, qa[1][1], zb, 0, 0, 0);
      s1[n] = zb;
    }

#pragma unroll
    for (int n = 0; n < 4; ++n)
#pragma unroll
      for (int r = 0; r < 4; ++r) {
        s0[n][r] = exp2raw(s0[n][r]);
        s1[n][r] = exp2raw(s1[n][r]);
      }

    bf16x8 pa[2][2];
    {
      uint32_t u00 = cvtpk(s0[0][0], s0[0][1]), u01 = cvtpk(s0[0][2], s0[0][3]);
      uint32_t u10 = cvtpk(s0[1][0], s0[1][1]), u11 = cvtpk(s0[1][2], s0[1][3]);
      uint32_t u20 = cvtpk(s0[2][0], s0[2][1]), u21 = cvtpk(s0[2][2], s0[2][3]);
      uint32_t u30 = cvtpk(s0[3][0], s0[3][1]), u31 = cvtpk(s0[3][2], s0[3][3]);
      asm volatile("v_permlane16_swap_b32 %0, %1" : "+v"(u00), "+v"(u20));
      asm volatile("v_permlane16_swap_b32 %0, %1" : "+v"(u01), "+v"(u21));
      asm volatile("v_permlane16_swap_b32 %0, %1" : "+v"(u10), "+v"(u30));
      asm volatile("v_permlane16_swap_b32 %0, %1" : "+v"(u11), "+v"(u31));
      int4 p0i = {(int)u00, (int)u01, (int)u20, (int)u21};
      int4 p1i = {(int)u10, (int)u11, (int)u30, (int)u31};
      pa[0][0] = __builtin_bit_cast(bf16x8, p0i);
      pa[0][1] = __builtin_bit_cast(bf16x8, p1i);
    }
    {
      uint32_t u00 = cvtpk(s1[0][0], s1[0][1]), u01 = cvtpk(s1[0][2], s1[0][3]);
      uint32_t u10 = cvtpk(s1[1][0], s1[1][1]), u11 = cvtpk(s1[1][2], s1[1][3]);
      uint32_t u20 = cvtpk(s1[2][0], s1[2][1]), u21 = cvtpk(s1[2][2], s1[2][3]);
      uint32_t u30 = cvtpk(s1[3][0], s1[3][1]), u31 = cvtpk(s1[3][2], s1[3][3]);
      asm volatile("v_permlane16_swap_b32 %0, %1" : "+v"(u00), "+v"(u20));
      asm volatile("v_permlane16_swap_b32 %0, %1" : "+v"(u01), "+v"(u21));
      asm volatile("v_permlane16_swap_b32 %0, %1" : "+v"(u10), "+v"(u30));
      asm volatile("v_permlane16_swap_b32 %0, %1" : "+v"(u11), "+v"(u31));
      int4 p0i = {(int)u00, (int)u01, (int)u20, (int)u21};
      int4 p1i = {(int)u10, (int)u11, (int)u30, (int)u31};
      pa[1][0] = __builtin_bit_cast(bf16x8, p0i);
      pa[1][1] = __builtin_bit_cast(bf16x8, p1i);
    }

    la0 = __builtin_amdgcn_mfma_f32_16x16x32_bf16(pa[0][0], ones, la0, 0, 0, 0);
    la0 = __builtin_amdgcn_mfma_f32_16x16x32_bf16(pa[0][1], ones, la0, 0, 0, 0);
    la1 = __builtin_amdgcn_mfma_f32_16x16x32_bf16(pa[1][0], ones, la1, 0, 0, 0);
    la1 = __builtin_amdgcn_mfma_f32_16x16x32_bf16(pa[1][1], ones, la1, 0, 0, 0);

#pragma unroll
    for (int dt = 0; dt < 4; ++dt) {
      bf16x8 vb0 = *reinterpret_cast<const bf16x8*>((const char*)vbuf[cur] + off0[dt]);
      bf16x8 vb1 = *reinterpret_cast<const bf16x8*>((const char*)vbuf[cur] + off1[dt]);
      o0[dt] = __builtin_amdgcn_mfma_f32_16x16x32_bf16(pa[0][0], vb0, o0[dt], 0, 0, 0);
      o0[dt] = __builtin_amdgcn_mfma_f32_16x16x32_bf16(pa[0][1], vb1, o0[dt], 0, 0, 0);
      o1[dt] = __builtin_amdgcn_mfma_f32_16x16x32_bf16(pa[1][0], vb0, o1[dt], 0, 0, 0);
      o1[dt] = __builtin_amdgcn_mfma_f32_16x16x32_bf16(pa[1][1], vb1, o1[dt], 0, 0, 0);
    }
  }

  u16* obase = (z == 0) ? P0 : (z == 1) ? P1 : (z == 2) ? P2 : P3;
#pragma unroll
  for (int r = 0; r < 4; ++r) {
    int orow0 = q0 + w * 32 + l4 * 4 + r;
#pragma unroll
    for (int dt = 0; dt < 4; ++dt) {
      obase[(size_t)orow0 * 512 + h * 64 + dt * 16 + l15] = f2bf(o0[dt][r]);
      obase[(size_t)(orow0 + 16) * 512 + h * 64 + dt * 16 + l15] = f2bf(o1[dt][r]);
    }
  }
  if (l15 == 0) {
    int q = q0 + w * 32 + l4 * 4;
#pragma unroll
    for (int r = 0; r < 4; ++r) {
      Lb[z * 32768 + h * 4096 + q + r] = la0[r];
      Lb[z * 32768 + h * 4096 + q + r + 16] = la1[r];
    }
  }
}

// ---------------- host launch -------------------------------------------------
extern "C" void kernel_launch(void* const* d_in, const int* in_sizes, int n_in,
                              void* d_out, int out_size, void* d_ws, size_t ws_size,
                              hipStream_t stream) {
  const float* x    = (const float*)d_in[0];
  const float* ctx  = (const float*)d_in[1];
  const float* gn_w = (const float*)d_in[2];
  const float* gn_b = (const float*)d_in[3];
  const float* wq   = (const float*)d_in[4];
  const float* bq   = (const float*)d_in[5];
  const float* wk   = (const float*)d_in[6];
  const float* bk   = (const float*)d_in[7];
  const float* wv   = (const float*)d_in[8];
  const float* bv   = (const float*)d_in[9];
  const float* wo   = (const float*)d_in[10];
  const float* bo   = (const float*)d_in[11];

  char* ws = (char*)d_ws;
  float* gpart  = (float*)ws;                     // 256 f32
  float* gpart2 = gpart + 256;                    // 256 f32
  u16* woB    = (u16*)(ws + 4096);                // kept live for proj
  u16* wqB    = woB + 512 * 512;                  // ---- dead-by-attn pool (12MB) ----
  u16* wkB    = wqB + 512 * 512;
  u16* wvB    = wkB + 512 * 768;
  u16* hT     = wvB + 512 * 768;                  // [4096][512]
  u16* ctxT   = hT + 4096 * 512;                  // [4096][768]
  u16* QT     = ctxT + 4096 * 768;                // [4096][512]
  u16* KT     = QT + 4096 * 512;                  // [4096][512]
  u16* Vb     = KT + 4096 * 512;                  // [512][4096]
  u16* OtT    = Vb + (size_t)512 * 4096;          // [4096][512] (dead; reused as P3)
  float* Lb   = (float*)(OtT + (size_t)4096 * 512);  // [4][8][4096]
  u16* P0     = wqB;                              // 4MB each, inside dead pool
  u16* P1     = P0 + (size_t)4096 * 512;
  u16* P2     = P1 + (size_t)4096 * 512;
  u16* P3     = OtT;

  prep_a<<<2304, 256, 0, stream>>>(x, gpart, gpart2, wq, wqB, wk, wkB, wv, wvB, wo, woB, ctx, ctxT);
  prep_b<<<512, 256, 0, stream>>>(x, hT, gn_w, gn_b, gpart, gpart2);

  gemm_all<<<512, 256, 0, stream>>>(hT, ctxT, wqB, wkB, wvB, QT, KT, Vb, bq, bk, bv);

  attn_kernel<<<1024, 256, 0, stream>>>(QT, KT, Vb, P0, P1, P2, P3, Lb);

  gemm_projF<<<512, 256, 0, stream>>>(woB, P0, P1, P2, P3, Lb, (float*)d_out, bo, x);
}

// Round 14
// 92.157 us; speedup vs baseline: 1.0374x; 1.0374x over previous
//
#include <hip/hip_runtime.h>
#include <cstdint>
#include <cstddef>

typedef __attribute__((ext_vector_type(8))) short bf16x8;
typedef __attribute__((ext_vector_type(4))) float f32x4;
typedef unsigned short u16;

#define QSCALE (0.125f * 1.44269504088896f)  // fold softmax scale + log2e into Q

__device__ inline u16 f2bf(float x) {
  uint32_t u = __builtin_bit_cast(uint32_t, x);
  u += 0x7FFFu + ((u >> 16) & 1u);
  return (u16)(u >> 16);
}
__device__ inline float bf2f(u16 v) {
  return __builtin_bit_cast(float, (uint32_t)v << 16);
}
__device__ inline uint32_t cvtpk(float a, float b) {
  uint32_t r;
  asm("v_cvt_pk_bf16_f32 %0, %1, %2" : "=v"(r) : "v"(a), "v"(b));
  return r;
}
__device__ inline float exp2raw(float x) {  // bare v_exp_f32, no libm fixup
  float r;
  asm("v_exp_f32 %0, %1" : "=v"(r) : "v"(x));
  return r;
}
__device__ inline void gload_lds16(const void* g, void* l) {
  __builtin_amdgcn_global_load_lds(
      (const __attribute__((address_space(1))) char*)g,
      (__attribute__((address_space(3))) char*)l, 16, 0, 0);
}

// ---------------- prep_a: gn partial sums + weight cvt + ctx transpose -------
// blocks [0,256): gn stats; [256,1536): cvt wq/wk/wv/wo; [1536,2304): ctxT
__global__ __launch_bounds__(256) void prep_a(const float* __restrict__ x,
                                              float* __restrict__ gpart,
                                              float* __restrict__ gpart2,
                                              const float* __restrict__ wq, u16* __restrict__ wqB,
                                              const float* __restrict__ wk, u16* __restrict__ wkB,
                                              const float* __restrict__ wv, u16* __restrict__ wvB,
                                              const float* __restrict__ wo, u16* __restrict__ woB,
                                              const float* __restrict__ ctx, u16* __restrict__ ctxT) {
  int b = blockIdx.x;
  int t = threadIdx.x;
  if (b < 256) {
    __shared__ float rs[4], rss[4];
    int g = b >> 3, sl = b & 7;
    const float* base = x + (size_t)g * 65536 + sl * 8192;
    float s = 0.f, ss = 0.f;
#pragma unroll
    for (int i = 0; i < 8; ++i) {
      float4 v = *reinterpret_cast<const float4*>(base + i * 1024 + t * 4);
      s += v.x + v.y + v.z + v.w;
      ss += v.x * v.x + v.y * v.y + v.z * v.z + v.w * v.w;
    }
    for (int d = 32; d; d >>= 1) {
      s += __shfl_down(s, d, 64);
      ss += __shfl_down(ss, d, 64);
    }
    int wid = t >> 6;
    if ((t & 63) == 0) { rs[wid] = s; rss[wid] = ss; }
    __syncthreads();
    if (t == 0) {
      gpart[b] = rs[0] + rs[1] + rs[2] + rs[3];
      gpart2[b] = rss[0] + rss[1] + rss[2] + rss[3];
    }
    return;
  }
  if (b < 1536) {
    int off = b - 256;
    const float* s; u16* d;
    if (off < 256)       { s = wq; d = wqB; }
    else if (off < 640)  { s = wk; d = wkB; off -= 256; }
    else if (off < 1024) { s = wv; d = wvB; off -= 640; }
    else                 { s = wo; d = woB; off -= 1024; }
    int i = (off * 256 + t) * 4;
    float4 v = *reinterpret_cast<const float4*>(s + i);
    u16 o[4] = {f2bf(v.x), f2bf(v.y), f2bf(v.z), f2bf(v.w)};
    *reinterpret_cast<uint2*>(d + i) = *reinterpret_cast<const uint2*>(o);
    return;
  }
  __shared__ float tile[64][65];
  int idx = b - 1536;
  int p0 = (idx & 63) * 64, c0 = (idx >> 6) * 64;
  int cl = t >> 4, pl = (t & 15) * 4;
#pragma unroll
  for (int rep = 0; rep < 4; ++rep) {
    int c = cl + rep * 16;
    float4 v = *reinterpret_cast<const float4*>(ctx + (size_t)(c0 + c) * 4096 + p0 + pl);
    tile[c][pl + 0] = v.x;
    tile[c][pl + 1] = v.y;
    tile[c][pl + 2] = v.z;
    tile[c][pl + 3] = v.w;
  }
  __syncthreads();
#pragma unroll
  for (int rep = 0; rep < 16; ++rep) {
    int id2 = rep * 256 + t;
    int pw = id2 >> 6, cw = id2 & 63;
    ctxT[(size_t)(p0 + pw) * 768 + c0 + cw] = f2bf(tile[cw][pw]);
  }
}

// ---------------- prep_b: x groupnorm + transpose to hT ----------------------
__global__ __launch_bounds__(256) void prep_b(const float* __restrict__ x,
                                              u16* __restrict__ hT,
                                              const float* __restrict__ gnw, const float* __restrict__ gnb,
                                              const float* __restrict__ gpart, const float* __restrict__ gpart2) {
  __shared__ float tile[64][65];
  __shared__ float smu[4], srs[4];
  int b = blockIdx.x;
  int t = threadIdx.x;
  int p0 = (b & 63) * 64, c0 = (b >> 6) * 64;
  if (t < 4) {
    int g = (c0 >> 4) + t;
    float S = 0.f, SS = 0.f;
#pragma unroll
    for (int sIdx = 0; sIdx < 8; ++sIdx) {
      S += gpart[g * 8 + sIdx];
      SS += gpart2[g * 8 + sIdx];
    }
    float mu = S * (1.f / 65536.f);
    float var = SS * (1.f / 65536.f) - mu * mu;
    smu[t] = mu;
    srs[t] = rsqrtf(var + 1e-5f);
  }
  __syncthreads();
  int cl = t >> 4, pl = (t & 15) * 4;
#pragma unroll
  for (int rep = 0; rep < 4; ++rep) {
    int c = cl + rep * 16;
    float4 v = *reinterpret_cast<const float4*>(x + (size_t)(c0 + c) * 4096 + p0 + pl);
    float s = gnw[c0 + c] * srs[rep];
    float f = gnb[c0 + c] - smu[rep] * s;
    tile[c][pl + 0] = v.x * s + f;
    tile[c][pl + 1] = v.y * s + f;
    tile[c][pl + 2] = v.z * s + f;
    tile[c][pl + 3] = v.w * s + f;
  }
  __syncthreads();
#pragma unroll
  for (int rep = 0; rep < 16; ++rep) {
    int idx = rep * 256 + t;
    int pw = idx >> 6, cw = idx & 63;
    hT[(size_t)(p0 + pw) * 512 + c0 + cw] = f2bf(tile[cw][pw]);
  }
}

// ---------------- NT GEMM body: D[i][j] = sum_k A[i][k]*B[j][k] --------------
// BM=128, BN=64. 2-buffer LDS (48KB -> 3 blocks/CU), 1-ahead prefetch.
template <int BIAS_MODE>
__device__ inline void gemm_body(u16* __restrict__ aT, u16* __restrict__ bT,
                                 const u16* __restrict__ A, const u16* __restrict__ B,
                                 u16* __restrict__ Dv,
                                 const float* __restrict__ bias,
                                 int Rb, int K, float oscale, int bx, int by) {
  const int t = threadIdx.x;
  const int lane = t & 63, w = t >> 6;
  const int wr = w >> 1, wc = w & 1;
  const int l15 = lane & 15, l4 = lane >> 4;
  const int i0 = by * 128, j0 = bx * 64;
  const int r_st = t >> 3, slot = t & 7;
  f32x4 acc[4][2] = {};

  auto stage = [&](int kt, int b) {
#pragma unroll
    for (int q = 0; q < 4; ++q) {
      int row = q * 32 + r_st;
      int koff = kt + ((slot ^ (row & 7)) * 8);
      gload_lds16(A + (size_t)(i0 + row) * K + koff, (char*)aT + b * 16384 + q * 4096 + w * 1024);
    }
#pragma unroll
    for (int q = 0; q < 2; ++q) {
      int row = q * 32 + r_st;
      int koff = kt + ((slot ^ (row & 7)) * 8);
      gload_lds16(B + (size_t)(j0 + row) * K + koff, (char*)bT + b * 8192 + q * 4096 + w * 1024);
    }
  };

  const int nt = K / 64;
  stage(0, 0);

  for (int tt = 0; tt < nt; ++tt) {
    const int cur = tt & 1;
    asm volatile("s_waitcnt vmcnt(0)\n\ts_barrier" ::: "memory");
    if (tt + 1 < nt) stage((tt + 1) * 64, cur ^ 1);

#pragma unroll
    for (int kk = 0; kk < 2; ++kk) {
      bf16x8 af[4], bfr[2];
#pragma unroll
      for (int m = 0; m < 4; ++m) {
        int row = wr * 64 + m * 16 + l15;
        int off = row * 128 + ((l4 * 16 + kk * 64) ^ ((row & 7) << 4));
        af[m] = *reinterpret_cast<const bf16x8*>((const char*)aT + cur * 16384 + off);
      }
#pragma unroll
      for (int n = 0; n < 2; ++n) {
        int row = wc * 32 + n * 16 + l15;
        int off = row * 128 + ((l4 * 16 + kk * 64) ^ ((row & 7) << 4));
        bfr[n] = *reinterpret_cast<const bf16x8*>((const char*)bT + cur * 8192 + off);
      }
#pragma unroll
      for (int m = 0; m < 4; ++m)
#pragma unroll
        for (int n = 0; n < 2; ++n)
          acc[m][n] = __builtin_amdgcn_mfma_f32_16x16x32_bf16(af[m], bfr[n], acc[m][n], 0, 0, 0);
    }
  }

#pragma unroll
  for (int m = 0; m < 4; ++m) {
    int ib = i0 + wr * 64 + m * 16 + l4 * 4;
#pragma unroll
    for (int n = 0; n < 2; ++n) {
      int j = j0 + wc * 32 + n * 16 + l15;
#pragma unroll
      for (int r = 0; r < 4; ++r) {
        int i = ib + r;
        float v = acc[m][n][r];
        if (BIAS_MODE == 0) v += bias[i];
        else v += bias[j];
        v *= oscale;
        Dv[(size_t)i * Rb + j] = f2bf(v);
      }
    }
  }
}

// merged Q+K+V projections, 1D grid of 768 blocks (48KB LDS -> 3/CU)
__global__ __launch_bounds__(256) void gemm_all(const u16* __restrict__ hT, const u16* __restrict__ ctxT,
                                                const u16* __restrict__ wqB, const u16* __restrict__ wkB,
                                                const u16* __restrict__ wvB,
                                                u16* __restrict__ QT, u16* __restrict__ KT, u16* __restrict__ Vb,
                                                const float* __restrict__ bq, const float* __restrict__ bk,
                                                const float* __restrict__ bv) {
  __shared__ u16 aT[2][128 * 64];
  __shared__ u16 bT[2][64 * 64];
  int b = blockIdx.x;
  if (b < 256)
    gemm_body<1>(&aT[0][0], &bT[0][0], hT, wqB, QT, bq, 512, 512, QSCALE, b & 7, b >> 3);
  else if (b < 512)
    gemm_body<1>(&aT[0][0], &bT[0][0], ctxT, wkB, KT, bk, 512, 768, 1.0f, (b - 256) & 7, (b - 256) >> 3);
  else
    gemm_body<0>(&aT[0][0], &bT[0][0], wvB, ctxT, Vb, bv, 4096, 768, 1.0f, (b - 512) & 63, (b - 512) >> 6);
}

// ---------------- fused combine + output projection + residual ---------------
__global__ __launch_bounds__(256) void gemm_projF(const u16* __restrict__ woB,
                                                  const u16* __restrict__ P0, const u16* __restrict__ P1,
                                                  const u16* __restrict__ P2, const u16* __restrict__ P3,
                                                  const float* __restrict__ Lb,
                                                  float* __restrict__ D, const float* __restrict__ bo,
                                                  const float* __restrict__ res) {
  __shared__ u16 aT[3][128 * 64];
  __shared__ u16 bT[2][64 * 64];
  __shared__ float sinv[512];  // [h][j_local]
  const int t = threadIdx.x;
  const int lane = t & 63, w = t >> 6;
  const int wr = w >> 1, wc = w & 1;
  const int l15 = lane & 15, l4 = lane >> 4;
  const int bx = blockIdx.x & 63, by = blockIdx.x >> 6;
  const int i0 = by * 128, j0 = bx * 64;
  const int r_st = t >> 3, slot = t & 7;

  {
#pragma unroll
    for (int r = 0; r < 2; ++r) {
      int idx = t * 2 + r;
      int hh = idx >> 6, jj = idx & 63;
      int o = hh * 4096 + j0 + jj;
      float den = Lb[o] + Lb[32768 + o] + Lb[65536 + o] + Lb[98304 + o];
      sinv[idx] = 1.f / den;
    }
  }

  auto stageA = [&](int kt, int b) {
#pragma unroll
    for (int q = 0; q < 4; ++q) {
      int row = q * 32 + r_st;
      int koff = kt + ((slot ^ (row & 7)) * 8);
      gload_lds16(woB + (size_t)(i0 + row) * 512 + koff, (char*)aT + b * 16384 + q * 4096 + w * 1024);
    }
  };

  const int brow = t >> 2;        // 0..63: token row within tile
  const int bc0 = (t & 3) * 2;    // first of 2 chunks (8 bf16 each)
  uint4 rv[2][4];
  auto loadB = [&](int kt) {
#pragma unroll
    for (int c = 0; c < 2; ++c) {
      size_t off = (size_t)(j0 + brow) * 512 + kt + (bc0 + c) * 8;
      rv[c][0] = *reinterpret_cast<const uint4*>(P0 + off);
      rv[c][1] = *reinterpret_cast<const uint4*>(P1 + off);
      rv[c][2] = *reinterpret_cast<const uint4*>(P2 + off);
      rv[c][3] = *reinterpret_cast<const uint4*>(P3 + off);
    }
  };
  auto writeB = [&](int kt, int buf) {
    float inv = sinv[((kt >> 6) << 6) + brow];
#pragma unroll
    for (int c = 0; c < 2; ++c) {
      uint32_t pk[4];
#pragma unroll
      for (int wi = 0; wi < 4; ++wi) {
        uint32_t w0 = (wi == 0) ? rv[c][0].x : (wi == 1) ? rv[c][0].y : (wi == 2) ? rv[c][0].z : rv[c][0].w;
        uint32_t w1 = (wi == 0) ? rv[c][1].x : (wi == 1) ? rv[c][1].y : (wi == 2) ? rv[c][1].z : rv[c][1].w;
        uint32_t w2 = (wi == 0) ? rv[c][2].x : (wi == 1) ? rv[c][2].y : (wi == 2) ? rv[c][2].z : rv[c][2].w;
        uint32_t w3 = (wi == 0) ? rv[c][3].x : (wi == 1) ? rv[c][3].y : (wi == 2) ? rv[c][3].z : rv[c][3].w;
        float lo = __builtin_bit_cast(float, w0 << 16) + __builtin_bit_cast(float, w1 << 16) +
                   __builtin_bit_cast(float, w2 << 16) + __builtin_bit_cast(float, w3 << 16);
        float hi = __builtin_bit_cast(float, w0 & 0xFFFF0000u) + __builtin_bit_cast(float, w1 & 0xFFFF0000u) +
                   __builtin_bit_cast(float, w2 & 0xFFFF0000u) + __builtin_bit_cast(float, w3 & 0xFFFF0000u);
        pk[wi] = cvtpk(lo * inv, hi * inv);
      }
      uint4 outv = {pk[0], pk[1], pk[2], pk[3]};
      int off = brow * 128 + (((bc0 + c) ^ (brow & 7)) * 16);
      *reinterpret_cast<uint4*>((char*)&bT[buf][0] + off) = outv;
    }
  };

  stageA(0, 0);
  stageA(64, 1);
  loadB(0);
  asm volatile("s_waitcnt vmcnt(4)" ::: "memory");
  writeB(0, 0);
  asm volatile("s_waitcnt lgkmcnt(0)\n\ts_barrier" ::: "memory");

  f32x4 acc[4][2] = {};
  for (int tt = 0; tt < 8; ++tt) {
    const int cur = tt & 1;
    if (tt + 1 < 8) loadB((tt + 1) * 64);

#pragma unroll
    for (int kk = 0; kk < 2; ++kk) {
      bf16x8 af[4], bfr[2];
#pragma unroll
      for (int m = 0; m < 4; ++m) {
        int row = wr * 64 + m * 16 + l15;
        int off = row * 128 + ((l4 * 16 + kk * 64) ^ ((row & 7) << 4));
        af[m] = *reinterpret_cast<const bf16x8*>((const char*)aT + (tt % 3) * 16384 + off);
      }
#pragma unroll
      for (int n = 0; n < 2; ++n) {
        int row = wc * 32 + n * 16 + l15;
        int off = row * 128 + ((l4 * 16 + kk * 64) ^ ((row & 7) << 4));
        bfr[n] = *reinterpret_cast<const bf16x8*>((const char*)&bT[cur][0] + off);
      }
#pragma unroll
      for (int m = 0; m < 4; ++m)
#pragma unroll
        for (int n = 0; n < 2; ++n)
          acc[m][n] = __builtin_amdgcn_mfma_f32_16x16x32_bf16(af[m], bfr[n], acc[m][n], 0, 0, 0);
    }

    if (tt + 2 < 8) stageA((tt + 2) * 64, (tt + 2) % 3);
    if (tt + 1 < 8) {
      if (tt + 2 < 8) asm volatile("s_waitcnt vmcnt(4)" ::: "memory");
      else            asm volatile("s_waitcnt vmcnt(0)" ::: "memory");
      writeB((tt + 1) * 64, cur ^ 1);
    }
    asm volatile("s_waitcnt lgkmcnt(0)\n\ts_barrier" ::: "memory");
  }

#pragma unroll
  for (int m = 0; m < 4; ++m) {
    int ib = i0 + wr * 64 + m * 16 + l4 * 4;
#pragma unroll
    for (int n = 0; n < 2; ++n) {
      int j = j0 + wc * 32 + n * 16 + l15;
#pragma unroll
      for (int r = 0; r < 4; ++r) {
        int i = ib + r;
        float v = acc[m][n][r] + bo[i] + res[(size_t)i * 4096 + j];
        D[(size_t)i * 4096 + j] = v;
      }
    }
  }
}

// ---------------- flash attention: fixed-offset softmax, KV-split x4 ---------
// (r10 kernel, verbatim — known race-free)
__global__ __launch_bounds__(256) void attn_kernel(const u16* __restrict__ QT,
                                                   const u16* __restrict__ KT,
                                                   const u16* __restrict__ V,
                                                   u16* __restrict__ P0, u16* __restrict__ P1,
                                                   u16* __restrict__ P2, u16* __restrict__ P3,
                                                   float* __restrict__ Lb) {
  __shared__ u16 kbuf[2][64 * 64];
  __shared__ u16 vbuf[2][64 * 64];
  const int t = threadIdx.x;
  const int lane = t & 63, w = t >> 6;
  const int l15 = lane & 15, l4 = lane >> 4;
  // XCD swizzle: 128 consecutive work-ids (one z-half, 4 heads) per XCD
  int id = blockIdx.x;
  id = (id & 7) * 128 + (id >> 3);
  const int z = id >> 8;
  const int h = (id >> 5) & 7;
  const int q0 = (id & 31) * 128;
  const int tile0 = z * 16;
  const int r_st = t >> 3, slot = t & 7;

  bf16x8 qa[2][2];
#pragma unroll
  for (int f = 0; f < 2; ++f) {
    int qrow = q0 + w * 32 + f * 16 + l15;
    qa[f][0] = *reinterpret_cast<const bf16x8*>(QT + (size_t)qrow * 512 + h * 64 + l4 * 8);
    qa[f][1] = *reinterpret_cast<const bf16x8*>(QT + (size_t)qrow * 512 + h * 64 + 32 + l4 * 8);
  }

  f32x4 o0[4] = {}, o1[4] = {};
  f32x4 la0 = {}, la1 = {};
  const short oneb = (short)0x3F80;  // bf16 1.0
  const bf16x8 ones = {oneb, oneb, oneb, oneb, oneb, oneb, oneb, oneb};

  int off0[4], off1[4];
#pragma unroll
  for (int n = 0; n < 4; ++n) {
    int row = n * 16 + l15, sw = (row & 7) << 4;
    off0[n] = row * 128 + ((l4 * 16) ^ sw);
    off1[n] = row * 128 + ((l4 * 16 + 64) ^ sw);
  }

  auto stageK = [&](int tile, int b) {
#pragma unroll
    for (int q = 0; q < 2; ++q) {
      int row = q * 32 + r_st;
      int so = (slot ^ (row & 7)) * 8;
      gload_lds16(KT + (size_t)(tile * 64 + row) * 512 + h * 64 + so,
                  (char*)kbuf[b] + q * 4096 + w * 1024);
    }
  };
  auto stageV = [&](int tile, int b) {
#pragma unroll
    for (int q = 0; q < 2; ++q) {
      int row = q * 32 + r_st;
      int so = ((((slot & 1) * 4 + (slot >> 1)) ^ (row & 7)) * 8);
      gload_lds16(V + (size_t)(h * 64 + row) * 4096 + tile * 64 + so,
                  (char*)vbuf[b] + q * 4096 + w * 1024);
    }
  };

  stageK(tile0, 0);
  stageV(tile0, 0);

#pragma unroll 2
  for (int kt = 0; kt < 16; ++kt) {
    const int cur = kt & 1;
    asm volatile("s_waitcnt vmcnt(0)\n\ts_barrier" ::: "memory");
    if (kt + 1 < 16) { stageK(tile0 + kt + 1, cur ^ 1); stageV(tile0 + kt + 1, cur ^ 1); }

    f32x4 s0[4], s1[4];
#pragma unroll
    for (int n = 0; n < 4; ++n) {
      bf16x8 kb0 = *reinterpret_cast<const bf16x8*>((const char*)kbuf[cur] + off0[n]);
      bf16x8 kb1 = *reinterpret_cast<const bf16x8*>((const char*)kbuf[cur] + off1[n]);
      f32x4 za = {};
      za = __builtin_amdgcn_mfma_f32_16x16x32_bf16(kb0, qa[0][0], za, 0, 0, 0);
      za = __builtin_amdgcn_mfma_f32_16x16x32_bf16(kb1, qa[0][1], za, 0, 0, 0);
      s0[n] = za;
      f32x4 zb = {};
      zb = __builtin_amdgcn_mfma_f32_16x16x32_bf16(kb0, qa[1][0], zb, 0, 0, 0);
      zb = __builtin_amdgcn_mfma_f32_16x16x32_bf16(kb1, qa[1][1], zb, 0, 0, 0);
      s1[n] = zb;
    }

    // P = exp2(S) directly (raw v_exp_f32), no offset bookkeeping
#pragma unroll
    for (int n = 0; n < 4; ++n)
#pragma unroll
      for (int r = 0; r < 4; ++r) {
        s0[n][r] = exp2raw(s0[n][r]);
        s1[n][r] = exp2raw(s1[n][r]);
      }

    bf16x8 pa[2][2];
    {
      uint32_t u00 = cvtpk(s0[0][0], s0[0][1]), u01 = cvtpk(s0[0][2], s0[0][3]);
      uint32_t u10 = cvtpk(s0[1][0], s0[1][1]), u11 = cvtpk(s0[1][2], s0[1][3]);
      uint32_t u20 = cvtpk(s0[2][0], s0[2][1]), u21 = cvtpk(s0[2][2], s0[2][3]);
      uint32_t u30 = cvtpk(s0[3][0], s0[3][1]), u31 = cvtpk(s0[3][2], s0[3][3]);
      asm volatile("v_permlane16_swap_b32 %0, %1" : "+v"(u00), "+v"(u20));
      asm volatile("v_permlane16_swap_b32 %0, %1" : "+v"(u01), "+v"(u21));
      asm volatile("v_permlane16_swap_b32 %0, %1" : "+v"(u10), "+v"(u30));
      asm volatile("v_permlane16_swap_b32 %0, %1" : "+v"(u11), "+v"(u31));
      int4 p0i = {(int)u00, (int)u01, (int)u20, (int)u21};
      int4 p1i = {(int)u10, (int)u11, (int)u30, (int)u31};
      pa[0][0] = __builtin_bit_cast(bf16x8, p0i);
      pa[0][1] = __builtin_bit_cast(bf16x8, p1i);
    }
    {
      uint32_t u00 = cvtpk(s1[0][0], s1[0][1]), u01 = cvtpk(s1[0][2], s1[0][3]);
      uint32_t u10 = cvtpk(s1[1][0], s1[1][1]), u11 = cvtpk(s1[1][2], s1[1][3]);
      uint32_t u20 = cvtpk(s1[2][0], s1[2][1]), u21 = cvtpk(s1[2][2], s1[2][3]);
      uint32_t u30 = cvtpk(s1[3][0], s1[3][1]), u31 = cvtpk(s1[3][2], s1[3][3]);
      asm volatile("v_permlane16_swap_b32 %0, %1" : "+v"(u00), "+v"(u20));
      asm volatile("v_permlane16_swap_b32 %0, %1" : "+v"(u01), "+v"(u21));
      asm volatile("v_permlane16_swap_b32 %0, %1" : "+v"(u10), "+v"(u30));
      asm volatile("v_permlane16_swap_b32 %0, %1" : "+v"(u11), "+v"(u31));
      int4 p0i = {(int)u00, (int)u01, (int)u20, (int)u21};
      int4 p1i = {(int)u10, (int)u11, (int)u30, (int)u31};
      pa[1][0] = __builtin_bit_cast(bf16x8, p0i);
      pa[1][1] = __builtin_bit_cast(bf16x8, p1i);
    }

    // row sums l += P . 1 via MFMA
    la0 = __builtin_amdgcn_mfma_f32_16x16x32_bf16(pa[0][0], ones, la0, 0, 0, 0);
    la0 = __builtin_amdgcn_mfma_f32_16x16x32_bf16(pa[0][1], ones, la0, 0, 0, 0);
    la1 = __builtin_amdgcn_mfma_f32_16x16x32_bf16(pa[1][0], ones, la1, 0, 0, 0);
    la1 = __builtin_amdgcn_mfma_f32_16x16x32_bf16(pa[1][1], ones, la1, 0, 0, 0);

    // O += P V
#pragma unroll
    for (int dt = 0; dt < 4; ++dt) {
      bf16x8 vb0 = *reinterpret_cast<const bf16x8*>((const char*)vbuf[cur] + off0[dt]);
      bf16x8 vb1 = *reinterpret_cast<const bf16x8*>((const char*)vbuf[cur] + off1[dt]);
      o0[dt] = __builtin_amdgcn_mfma_f32_16x16x32_bf16(pa[0][0], vb0, o0[dt], 0, 0, 0);
      o0[dt] = __builtin_amdgcn_mfma_f32_16x16x32_bf16(pa[0][1], vb1, o0[dt], 0, 0, 0);
      o1[dt] = __builtin_amdgcn_mfma_f32_16x16x32_bf16(pa[1][0], vb0, o1[dt], 0, 0, 0);
      o1[dt] = __builtin_amdgcn_mfma_f32_16x16x32_bf16(pa[1][1], vb1, o1[dt], 0, 0, 0);
    }
  }

  u16* obase = (z == 0) ? P0 : (z == 1) ? P1 : (z == 2) ? P2 : P3;
#pragma unroll
  for (int r = 0; r < 4; ++r) {
    int orow0 = q0 + w * 32 + l4 * 4 + r;
#pragma unroll
    for (int dt = 0; dt < 4; ++dt) {
      obase[(size_t)orow0 * 512 + h * 64 + dt * 16 + l15] = f2bf(o0[dt][r]);
      obase[(size_t)(orow0 + 16) * 512 + h * 64 + dt * 16 + l15] = f2bf(o1[dt][r]);
    }
  }
  if (l15 == 0) {
    int q = q0 + w * 32 + l4 * 4;
#pragma unroll
    for (int r = 0; r < 4; ++r) {
      Lb[z * 32768 + h * 4096 + q + r] = la0[r];
      Lb[z * 32768 + h * 4096 + q + r + 16] = la1[r];
    }
  }
}

// ---------------- host launch -------------------------------------------------
extern "C" void kernel_launch(void* const* d_in, const int* in_sizes, int n_in,
                              void* d_out, int out_size, void* d_ws, size_t ws_size,
                              hipStream_t stream) {
  const float* x    = (const float*)d_in[0];
  const float* ctx  = (const float*)d_in[1];
  const float* gn_w = (const float*)d_in[2];
  const float* gn_b = (const float*)d_in[3];
  const float* wq   = (const float*)d_in[4];
  const float* bq   = (const float*)d_in[5];
  const float* wk   = (const float*)d_in[6];
  const float* bk   = (const float*)d_in[7];
  const float* wv   = (const float*)d_in[8];
  const float* bv   = (const float*)d_in[9];
  const float* wo   = (const float*)d_in[10];
  const float* bo   = (const float*)d_in[11];

  char* ws = (char*)d_ws;
  float* gpart  = (float*)ws;                     // 256 f32
  float* gpart2 = gpart + 256;                    // 256 f32
  u16* woB    = (u16*)(ws + 4096);                // kept live for proj
  u16* wqB    = woB + 512 * 512;                  // ---- dead-by-attn pool (12MB) ----
  u16* wkB    = wqB + 512 * 512;
  u16* wvB    = wkB + 512 * 768;
  u16* hT     = wvB + 512 * 768;                  // [4096][512]
  u16* ctxT   = hT + 4096 * 512;                  // [4096][768]
  u16* QT     = ctxT + 4096 * 768;                // [4096][512]
  u16* KT     = QT + 4096 * 512;                  // [4096][512]
  u16* Vb     = KT + 4096 * 512;                  // [512][4096]
  u16* OtT    = Vb + (size_t)512 * 4096;          // [4096][512] (dead; reused as P3)
  float* Lb   = (float*)(OtT + (size_t)4096 * 512);  // [4][8][4096]
  u16* P0     = wqB;                              // 4MB each, inside dead pool
  u16* P1     = P0 + (size_t)4096 * 512;
  u16* P2     = P1 + (size_t)4096 * 512;
  u16* P3     = OtT;

  prep_a<<<2304, 256, 0, stream>>>(x, gpart, gpart2, wq, wqB, wk, wkB, wv, wvB, wo, woB, ctx, ctxT);
  prep_b<<<512, 256, 0, stream>>>(x, hT, gn_w, gn_b, gpart, gpart2);

  gemm_all<<<768, 256, 0, stream>>>(hT, ctxT, wqB, wkB, wvB, QT, KT, Vb, bq, bk, bv);

  attn_kernel<<<1024, 256, 0, stream>>>(QT, KT, Vb, P0, P1, P2, P3, Lb);

  gemm_projF<<<256, 256, 0, stream>>>(woB, P0, P1, P2, P3, Lb, (float*)d_out, bo, x);
}